// Round 4
// baseline (223.806 us; speedup 1.0000x reference)
//
#include <hip/hip_runtime.h>
#include <hip/hip_cooperative_groups.h>

namespace cg = cooperative_groups;

#define H     300
#define MID   100
#define NN    1024
#define NP1   1025
#define SST   1088   // padded s2T row stride (4352 B, 256B-aligned rows)
#define GRID  512

static __device__ __forceinline__ float sig_pre(float x, float apre) {
    const float NL = -1.4426950408889634f;
    return __builtin_amdgcn_rcpf(1.0f + __builtin_amdgcn_exp2f(__builtin_fmaf(x, NL, apre)));
}

// paired contribution: acc += w_a*sigmoid + w_b*sigmoid with ONE rcp.
// w_a/(1+e_a) + w_b/(1+e_b) = (w_a*B + w_b*A) / (A*B),  A=1+e_a, B=1+e_b
static __device__ __forceinline__ void pair_acc(
    float x_a, float x_b, float apre_a, float apre_b,
    float w_a, float w_b, float& acc)
{
    const float NL = -1.4426950408889634f;
    const float ea = __builtin_amdgcn_exp2f(__builtin_fmaf(x_a, NL, apre_a));
    const float eb = __builtin_amdgcn_exp2f(__builtin_fmaf(x_b, NL, apre_b));
    const float A = 1.0f + ea, B = 1.0f + eb;
    acc = __builtin_fmaf(__builtin_fmaf(w_a, B, w_b * A),
                         __builtin_amdgcn_rcpf(A * B), acc);
}

__global__ __launch_bounds__(256, 2) void fused_kernel(
    const float* __restrict__ sentence,
    const float* __restrict__ W1,
    const float* __restrict__ b1,
    const float* __restrict__ W2,
    const float* __restrict__ b2,
    const int*   __restrict__ target,
    float* __restrict__ out,
    float* __restrict__ s1b,
    float* __restrict__ s2T,
    float* __restrict__ W1T)
{
    cg::grid_group grid = cg::this_grid();

    __shared__ float rA[H];
    __shared__ float rB[H];
    __shared__ float4 aw4[MID];        // {apreA[m], apreB[m], W2[m], 0}
    __shared__ float tmpA[MID], tmpB[MID];
    __shared__ float r1[4], r2[4], r3[4];
    __shared__ float bc[4];
    __shared__ float sc4sh[2];

    const int b   = blockIdx.x;
    const int tid = threadIdx.x;
    const int lane = tid & 63, wv = tid >> 6;
    const float NL  = -1.4426950408889634f;
    const float L2E =  1.4426950408889634f;

    // ================= Phase A: transpose W1 (100x600) -> W1T (600x100) ====
    // block b handles column c=b; blocks 0..87 also column 512+b. Writes coalesced.
    if (tid < MID) {
        const int c = b;
        W1T[c * MID + tid] = W1[tid * (2 * H) + c];
        if (b < 2 * H - GRID) {
            const int c2 = GRID + b;
            W1T[c2 * MID + tid] = W1[tid * (2 * H) + c2];
        }
    }
    if (b == 0 && tid == 0) out[0] = 0.0f;   // loss accumulator
    grid.sync();

    // ================= Phase B: precompute s1b / s2T ========================
    // items iA=2b, iB=2b+1. Group0 (tid<128): first W1 half -> s1b rows.
    // Group1 (tid>=128): second half -> s2T cols. Shared sentence rows in LDS.
    const int iA = 2 * b, iB = iA + 1;
    {
        const float* sA = sentence + (long)iA * H;
        const float* sB = sentence + (long)iB * H;
        for (int idx = tid; idx < 2 * H; idx += 256) {
            if (idx < H) rA[idx] = sA[idx];
            else         rB[idx - H] = sB[idx - H];
        }
        __syncthreads();

        const int g = tid >> 7;         // 0 or 1
        const int m = tid & 127;
        if (m < MID) {
            const float* Wb = W1T + (g ? (H * MID) : 0) + m;
            float aA = 0.f, aB = 0.f;
            #pragma unroll 4
            for (int h = 0; h < H; ++h) {
                const float w = Wb[h * MID];
                aA = __builtin_fmaf(w, rA[h], aA);
                aB = __builtin_fmaf(w, rB[h], aB);
            }
            if (g == 0) {
                const float bb = b1[m];
                s1b[iA * MID + m] = aA + bb;
                s1b[iB * MID + m] = aB + bb;
            } else {
                s2T[(long)m * SST + (iA + 1)] = aA;
                s2T[(long)m * SST + (iB + 1)] = aB;
                if (b == 0) s2T[(long)m * SST] = 0.0f;   // pm[0] = zeros column
            }
        }
    }
    grid.sync();

    // ================= Phase C: pairwise scores + loss + softmax ============
    if (tid < MID)
        aw4[tid] = make_float4(s1b[iA * MID + tid] * NL,
                               s1b[iB * MID + tid] * NL,
                               W2[tid], 0.f);
    const float b2v = b2[0];
    __syncthreads();

    const long colbase = (long)(tid << 2);
    #define LDX(m) (*(const float4*)(s2T + (long)(m) * SST + colbase))

    float aA0 = 0.f, aA1 = 0.f, aA2 = 0.f, aA3 = 0.f;
    float aB0 = 0.f, aB1 = 0.f, aB2 = 0.f, aB3 = 0.f;

    #define PBODY(WA, WB, XA, XB)                                          \
        do {                                                               \
            pair_acc((XA).x, (XB).x, (WA).x, (WB).x, (WA).z, (WB).z, aA0); \
            pair_acc((XA).y, (XB).y, (WA).x, (WB).x, (WA).z, (WB).z, aA1); \
            pair_acc((XA).z, (XB).z, (WA).x, (WB).x, (WA).z, (WB).z, aA2); \
            pair_acc((XA).w, (XB).w, (WA).x, (WB).x, (WA).z, (WB).z, aA3); \
            pair_acc((XA).x, (XB).x, (WA).y, (WB).y, (WA).z, (WB).z, aB0); \
            pair_acc((XA).y, (XB).y, (WA).y, (WB).y, (WA).z, (WB).z, aB1); \
            pair_acc((XA).z, (XB).z, (WA).y, (WB).y, (WA).z, (WB).z, aB2); \
            pair_acc((XA).w, (XB).w, (WA).y, (WB).y, (WA).z, (WB).z, aB3); \
        } while (0)

    // 50 m-pairs, distance-2 software pipeline on the pair loads
    float4 xa0 = LDX(0), xb0 = LDX(1);
    float4 xa1 = LDX(2), xb1 = LDX(3);
    #pragma unroll 2
    for (int p = 0; p < 48; ++p) {
        const float4 xan = LDX(2 * p + 4);
        const float4 xbn = LDX(2 * p + 5);
        const float4 wA = aw4[2 * p];
        const float4 wB = aw4[2 * p + 1];
        PBODY(wA, wB, xa0, xb0);
        xa0 = xa1; xb0 = xb1; xa1 = xan; xb1 = xbn;
    }
    {
        float4 wA = aw4[96], wB = aw4[97];
        PBODY(wA, wB, xa0, xb0);
        wA = aw4[98]; wB = aw4[99];
        PBODY(wA, wB, xa1, xb1);
    }

    const float scA0 = aA0 + b2v, scA1 = aA1 + b2v, scA2 = aA2 + b2v, scA3 = aA3 + b2v;
    const float scB0 = aB0 + b2v, scB1 = aB1 + b2v, scB2 = aB2 + b2v, scB3 = aB3 + b2v;

    // ---- remainder column j = 1024 ----
    if (tid < MID) {
        const float4 w = aw4[tid];
        const float x = s2T[(long)tid * SST + 1024];
        tmpA[tid] = w.z * sig_pre(x, w.x);
        tmpB[tid] = w.z * sig_pre(x, w.y);
    }
    __syncthreads();
    if (wv == 0) {
        float v = tmpA[lane] + ((lane < MID - 64) ? tmpA[lane + 64] : 0.f);
        #pragma unroll
        for (int off = 32; off > 0; off >>= 1) v += __shfl_down(v, off);
        if (lane == 0) sc4sh[0] = v + b2v;
    } else if (wv == 1) {
        float v = tmpB[lane] + ((lane < MID - 64) ? tmpB[lane + 64] : 0.f);
        #pragma unroll
        for (int off = 32; off > 0; off >>= 1) v += __shfl_down(v, off);
        if (lane == 0) sc4sh[1] = v + b2v;
    }
    __syncthreads();
    const float sc4A = sc4sh[0];
    const float sc4B = sc4sh[1];

    // ---- loss + row-max ----
    const int tgtA = target[iA], tgtB = target[iB];
    const int j0 = tid << 2;
    float ls = fabsf(scA0 - ((j0     == tgtA) ? 1.f : 0.f))
             + fabsf(scA1 - ((j0 + 1 == tgtA) ? 1.f : 0.f))
             + fabsf(scA2 - ((j0 + 2 == tgtA) ? 1.f : 0.f))
             + fabsf(scA3 - ((j0 + 3 == tgtA) ? 1.f : 0.f))
             + fabsf(scB0 - ((j0     == tgtB) ? 1.f : 0.f))
             + fabsf(scB1 - ((j0 + 1 == tgtB) ? 1.f : 0.f))
             + fabsf(scB2 - ((j0 + 2 == tgtB) ? 1.f : 0.f))
             + fabsf(scB3 - ((j0 + 3 == tgtB) ? 1.f : 0.f));
    float mA = fmaxf(fmaxf(scA0, scA1), fmaxf(scA2, scA3));
    float mB = fmaxf(fmaxf(scB0, scB1), fmaxf(scB2, scB3));
    if (tid == 0) {
        ls += fabsf(sc4A - ((1024 == tgtA) ? 1.f : 0.f))
            + fabsf(sc4B - ((1024 == tgtB) ? 1.f : 0.f));
        mA = fmaxf(mA, sc4A);
        mB = fmaxf(mB, sc4B);
    }
    #pragma unroll
    for (int off = 32; off > 0; off >>= 1) {
        ls += __shfl_down(ls, off);
        mA = fmaxf(mA, __shfl_down(mA, off));
        mB = fmaxf(mB, __shfl_down(mB, off));
    }
    if (lane == 0) { r1[wv] = ls; r2[wv] = mA; r3[wv] = mB; }
    __syncthreads();
    if (tid == 0) {
        atomicAdd(out, (r1[0] + r1[1] + r1[2] + r1[3]) * (1.0f / ((float)NN * (float)NP1)));
        bc[0] = fmaxf(fmaxf(r2[0], r2[1]), fmaxf(r2[2], r2[3]));
        bc[1] = fmaxf(fmaxf(r3[0], r3[1]), fmaxf(r3[2], r3[3]));
    }
    __syncthreads();
    const float rmA = bc[0], rmB = bc[1];

    // ---- exp + sum per row ----
    const float eA0 = __builtin_amdgcn_exp2f((scA0 - rmA) * L2E);
    const float eA1 = __builtin_amdgcn_exp2f((scA1 - rmA) * L2E);
    const float eA2 = __builtin_amdgcn_exp2f((scA2 - rmA) * L2E);
    const float eA3 = __builtin_amdgcn_exp2f((scA3 - rmA) * L2E);
    const float eB0 = __builtin_amdgcn_exp2f((scB0 - rmB) * L2E);
    const float eB1 = __builtin_amdgcn_exp2f((scB1 - rmB) * L2E);
    const float eB2 = __builtin_amdgcn_exp2f((scB2 - rmB) * L2E);
    const float eB3 = __builtin_amdgcn_exp2f((scB3 - rmB) * L2E);
    float e4A = 0.f, e4B = 0.f;
    if (tid == 0) {
        e4A = __builtin_amdgcn_exp2f((sc4A - rmA) * L2E);
        e4B = __builtin_amdgcn_exp2f((sc4B - rmB) * L2E);
    }
    float esA = eA0 + eA1 + eA2 + eA3 + e4A;
    float esB = eB0 + eB1 + eB2 + eB3 + e4B;
    #pragma unroll
    for (int off = 32; off > 0; off >>= 1) {
        esA += __shfl_down(esA, off);
        esB += __shfl_down(esB, off);
    }
    if (lane == 0) { r1[wv] = esA; r2[wv] = esB; }
    __syncthreads();
    if (tid == 0) {
        bc[2] = 1.0f / (r1[0] + r1[1] + r1[2] + r1[3]);
        bc[3] = 1.0f / (r2[0] + r2[1] + r2[2] + r2[3]);
    }
    __syncthreads();
    const float invA = bc[2], invB = bc[3];

    // ---- write softmax rows ----
    float* orowA = out + 1 + (long)iA * NP1;
    float* orowB = out + 1 + (long)iB * NP1;
    orowA[j0]     = eA0 * invA;
    orowA[j0 + 1] = eA1 * invA;
    orowA[j0 + 2] = eA2 * invA;
    orowA[j0 + 3] = eA3 * invA;
    orowB[j0]     = eB0 * invB;
    orowB[j0 + 1] = eB1 * invB;
    orowB[j0 + 2] = eB2 * invB;
    orowB[j0 + 3] = eB3 * invB;
    if (tid == 0) {
        orowA[1024] = e4A * invA;
        orowB[1024] = e4B * invB;
    }
    #undef PBODY
    #undef LDX
}

extern "C" void kernel_launch(void* const* d_in, const int* in_sizes, int n_in,
                              void* d_out, int out_size, void* d_ws, size_t ws_size,
                              hipStream_t stream) {
    const float* sentence = (const float*)d_in[0];
    const int*   target   = (const int*)  d_in[1];
    const float* W1       = (const float*)d_in[2];
    const float* b1       = (const float*)d_in[3];
    const float* W2       = (const float*)d_in[4];
    const float* b2       = (const float*)d_in[5];
    float* out = (float*)d_out;

    float* s1b = (float*)d_ws;                 // 1024*100
    float* s2T = s1b + NN * MID;               // 100*1088
    float* W1T = s2T + MID * SST;              // 600*100

    void* args[] = { (void*)&sentence, (void*)&W1, (void*)&b1, (void*)&W2,
                     (void*)&b2, (void*)&target, (void*)&out,
                     (void*)&s1b, (void*)&s2T, (void*)&W1T };
    hipLaunchCooperativeKernel((const void*)fused_kernel, dim3(GRID), dim3(256),
                               args, 0, stream);
}

// Round 5
// 124.731 us; speedup vs baseline: 1.7943x; 1.7943x over previous
//
#include <hip/hip_runtime.h>

#define H     300
#define MID   100
#define NN    1024
#define NP1   1025
#define SST   1088   // padded s2T row stride (4352 B, 256B-aligned rows)

// paired contribution: acc += w_a*sig(x_a,apre_a) + w_b*sig(x_b,apre_b), ONE rcp:
// w_a/A + w_b/B = (w_a*B + w_b*A) * rcp(A*B),  A=1+exp2(fma(x_a,NL,apre_a)), etc.
static __device__ __forceinline__ void pair_acc(
    float x_a, float x_b, float apre_a, float apre_b,
    float w_a, float w_b, float& acc)
{
    const float NL = -1.4426950408889634f;
    const float A = 1.0f + __builtin_amdgcn_exp2f(__builtin_fmaf(x_a, NL, apre_a));
    const float B = 1.0f + __builtin_amdgcn_exp2f(__builtin_fmaf(x_b, NL, apre_b));
    acc = __builtin_fmaf(__builtin_fmaf(w_a, B, w_b * A),
                         __builtin_amdgcn_rcpf(A * B), acc);
}

static __device__ __forceinline__ float sig_pre(float x, float apre) {
    const float NL = -1.4426950408889634f;
    return __builtin_amdgcn_rcpf(1.0f + __builtin_amdgcn_exp2f(__builtin_fmaf(x, NL, apre)));
}

// ---------------------------------------------------------------------------
// Kernel T: transpose W1 (100 x 600) -> W1T (600 x 100), LDS-tiled.
// Also zeroes the loss accumulator out[0] (stream-ordered before main_kernel).
// ---------------------------------------------------------------------------
__global__ __launch_bounds__(256) void transpose_kernel(
    const float* __restrict__ W1, float* __restrict__ W1T, float* __restrict__ out)
{
    __shared__ float tile[MID][65];
    const int c0 = blockIdx.x * 64;
    const int tid = threadIdx.x;
    if (blockIdx.x == 0 && tid == 0) out[0] = 0.0f;
    for (int idx = tid; idx < MID * 64; idx += 256) {
        const int m = idx >> 6, cc = idx & 63, c = c0 + cc;
        if (c < 2 * H) tile[m][cc] = W1[m * (2 * H) + c];
    }
    __syncthreads();
    for (int idx = tid; idx < 64 * MID; idx += 256) {
        const int cc = idx / MID, m = idx - cc * MID, c = c0 + cc;
        if (c < 2 * H) W1T[c * MID + m] = tile[m][cc];
    }
}

// ---------------------------------------------------------------------------
// Kernel A: precompute. 512 blocks x 256 threads; block b -> items iA=2b, iB.
// Group g = tid>>7 handles W1 half g (300 loads/thread, coalesced W1T reads).
// ---------------------------------------------------------------------------
__global__ __launch_bounds__(256) void precompute_kernel(
    const float* __restrict__ sentence,
    const float* __restrict__ W1T,
    const float* __restrict__ b1,
    float* __restrict__ s1b,
    float* __restrict__ s2T)
{
    __shared__ float rA[H];
    __shared__ float rB[H];
    const int tid = threadIdx.x;
    const int iA = blockIdx.x * 2, iB = iA + 1;

    const float* sA = sentence + (long)iA * H;
    const float* sB = sentence + (long)iB * H;
    for (int idx = tid; idx < 2 * H; idx += 256) {
        if (idx < H) rA[idx] = sA[idx];
        else         rB[idx - H] = sB[idx - H];
    }
    __syncthreads();

    const int g = tid >> 7;
    const int m = tid & 127;
    if (m < MID) {
        const float* Wb = W1T + (g ? (H * MID) : 0) + m;
        float aA = 0.f, aB = 0.f;
        #pragma unroll 4
        for (int h = 0; h < H; ++h) {
            const float w = Wb[h * MID];
            aA = __builtin_fmaf(w, rA[h], aA);
            aB = __builtin_fmaf(w, rB[h], aB);
        }
        if (g == 0) {
            const float bb = b1[m];
            s1b[iA * MID + m] = aA + bb;
            s1b[iB * MID + m] = aB + bb;
        } else {
            s2T[(long)m * SST + (iA + 1)] = aA;
            s2T[(long)m * SST + (iB + 1)] = aB;
            if (blockIdx.x == 0) s2T[(long)m * SST] = 0.0f;
        }
    }
}

// ---------------------------------------------------------------------------
// Kernel B: 512 blocks x 512 threads (16 waves/CU = 4 waves/SIMD).
// Block handles rows iA=2b, iB=2b+1; thread handles 2 consecutive cols
// (j = 2*tid, 2*tid+1) via float2 loads (4 sigmoids/load, 210 MB L2 traffic).
// m-loop processed in pairs with the shared-rcp trick; distance-2 pipeline.
// ---------------------------------------------------------------------------
__global__ __launch_bounds__(512, 4) void main_kernel(
    const float* __restrict__ s1b,
    const float* __restrict__ s2T,
    const float* __restrict__ W2,
    const float* __restrict__ b2,
    const int*   __restrict__ target,
    float* __restrict__ out)
{
    __shared__ float4 aw4[MID];        // {apreA[m], apreB[m], W2[m], 0}
    __shared__ float tmpA[MID], tmpB[MID];
    __shared__ float r1[8], r2[8], r3[8];
    __shared__ float bc[4];
    __shared__ float sc4sh[2];

    const int iA = blockIdx.x * 2, iB = iA + 1;
    const int tid = threadIdx.x;
    const int lane = tid & 63, wv = tid >> 6;
    const float NL  = -1.4426950408889634f;
    const float L2E =  1.4426950408889634f;

    if (tid < MID)
        aw4[tid] = make_float4(s1b[iA * MID + tid] * NL,
                               s1b[iB * MID + tid] * NL,
                               W2[tid], 0.f);
    const float b2v = b2[0];
    __syncthreads();

    const long colbase = (long)(tid << 1);
    #define LDX(m) (*(const float2*)(s2T + (long)(m) * SST + colbase))

    float aA0 = 0.f, aA1 = 0.f, aB0 = 0.f, aB1 = 0.f;

    // pairs p: m = 2p, 2p+1. Prefetch 2 pairs ahead.
    float2 x0 = LDX(0), x1 = LDX(1);
    float2 x2 = LDX(2), x3 = LDX(3);
    #pragma unroll 2
    for (int p = 0; p < 48; ++p) {
        const float2 xn0 = LDX(2 * p + 4);
        const float2 xn1 = LDX(2 * p + 5);
        const float4 wA = aw4[2 * p];
        const float4 wB = aw4[2 * p + 1];
        pair_acc(x0.x, x1.x, wA.x, wB.x, wA.z, wB.z, aA0);
        pair_acc(x0.y, x1.y, wA.x, wB.x, wA.z, wB.z, aA1);
        pair_acc(x0.x, x1.x, wA.y, wB.y, wA.z, wB.z, aB0);
        pair_acc(x0.y, x1.y, wA.y, wB.y, wA.z, wB.z, aB1);
        x0 = x2; x1 = x3; x2 = xn0; x3 = xn1;
    }
    {
        float4 wA = aw4[96], wB = aw4[97];
        pair_acc(x0.x, x1.x, wA.x, wB.x, wA.z, wB.z, aA0);
        pair_acc(x0.y, x1.y, wA.x, wB.x, wA.z, wB.z, aA1);
        pair_acc(x0.x, x1.x, wA.y, wB.y, wA.z, wB.z, aB0);
        pair_acc(x0.y, x1.y, wA.y, wB.y, wA.z, wB.z, aB1);
        wA = aw4[98]; wB = aw4[99];
        pair_acc(x2.x, x3.x, wA.x, wB.x, wA.z, wB.z, aA0);
        pair_acc(x2.y, x3.y, wA.x, wB.x, wA.z, wB.z, aA1);
        pair_acc(x2.x, x3.x, wA.y, wB.y, wA.z, wB.z, aB0);
        pair_acc(x2.y, x3.y, wA.y, wB.y, wA.z, wB.z, aB1);
    }

    const float scA0 = aA0 + b2v, scA1 = aA1 + b2v;
    const float scB0 = aB0 + b2v, scB1 = aB1 + b2v;

    // ---- remainder column j = 1024 ----
    if (tid < MID) {
        const float4 w = aw4[tid];
        const float x = s2T[(long)tid * SST + 1024];
        tmpA[tid] = w.z * sig_pre(x, w.x);
        tmpB[tid] = w.z * sig_pre(x, w.y);
    }
    __syncthreads();
    if (wv == 0) {
        float v = tmpA[lane] + ((lane < MID - 64) ? tmpA[lane + 64] : 0.f);
        #pragma unroll
        for (int off = 32; off > 0; off >>= 1) v += __shfl_down(v, off);
        if (lane == 0) sc4sh[0] = v + b2v;
    } else if (wv == 1) {
        float v = tmpB[lane] + ((lane < MID - 64) ? tmpB[lane + 64] : 0.f);
        #pragma unroll
        for (int off = 32; off > 0; off >>= 1) v += __shfl_down(v, off);
        if (lane == 0) sc4sh[1] = v + b2v;
    }
    __syncthreads();
    const float sc4A = sc4sh[0];
    const float sc4B = sc4sh[1];

    // ---- loss + row-max ----
    const int tgtA = target[iA], tgtB = target[iB];
    const int j0 = tid << 1;
    float ls = fabsf(scA0 - ((j0     == tgtA) ? 1.f : 0.f))
             + fabsf(scA1 - ((j0 + 1 == tgtA) ? 1.f : 0.f))
             + fabsf(scB0 - ((j0     == tgtB) ? 1.f : 0.f))
             + fabsf(scB1 - ((j0 + 1 == tgtB) ? 1.f : 0.f));
    float mA = fmaxf(scA0, scA1);
    float mB = fmaxf(scB0, scB1);
    if (tid == 0) {
        ls += fabsf(sc4A - ((1024 == tgtA) ? 1.f : 0.f))
            + fabsf(sc4B - ((1024 == tgtB) ? 1.f : 0.f));
        mA = fmaxf(mA, sc4A);
        mB = fmaxf(mB, sc4B);
    }
    #pragma unroll
    for (int off = 32; off > 0; off >>= 1) {
        ls += __shfl_down(ls, off);
        mA = fmaxf(mA, __shfl_down(mA, off));
        mB = fmaxf(mB, __shfl_down(mB, off));
    }
    if (lane == 0) { r1[wv] = ls; r2[wv] = mA; r3[wv] = mB; }
    __syncthreads();
    if (tid == 0) {
        float L = 0.f, MA = -1e30f, MB = -1e30f;
        #pragma unroll
        for (int k = 0; k < 8; ++k) {
            L += r1[k];
            MA = fmaxf(MA, r2[k]);
            MB = fmaxf(MB, r3[k]);
        }
        atomicAdd(out, L * (1.0f / ((float)NN * (float)NP1)));
        bc[0] = MA;
        bc[1] = MB;
    }
    __syncthreads();
    const float rmA = bc[0], rmB = bc[1];

    // ---- exp + sum per row ----
    const float eA0 = __builtin_amdgcn_exp2f((scA0 - rmA) * L2E);
    const float eA1 = __builtin_amdgcn_exp2f((scA1 - rmA) * L2E);
    const float eB0 = __builtin_amdgcn_exp2f((scB0 - rmB) * L2E);
    const float eB1 = __builtin_amdgcn_exp2f((scB1 - rmB) * L2E);
    float e4A = 0.f, e4B = 0.f;
    if (tid == 0) {
        e4A = __builtin_amdgcn_exp2f((sc4A - rmA) * L2E);
        e4B = __builtin_amdgcn_exp2f((sc4B - rmB) * L2E);
    }
    float esA = eA0 + eA1 + e4A;
    float esB = eB0 + eB1 + e4B;
    #pragma unroll
    for (int off = 32; off > 0; off >>= 1) {
        esA += __shfl_down(esA, off);
        esB += __shfl_down(esB, off);
    }
    if (lane == 0) { r1[wv] = esA; r2[wv] = esB; }
    __syncthreads();
    if (tid == 0) {
        float SA = 0.f, SB = 0.f;
        #pragma unroll
        for (int k = 0; k < 8; ++k) { SA += r1[k]; SB += r2[k]; }
        bc[2] = 1.0f / SA;
        bc[3] = 1.0f / SB;
    }
    __syncthreads();
    const float invA = bc[2], invB = bc[3];

    // ---- write softmax rows ----
    float* orowA = out + 1 + (long)iA * NP1;
    float* orowB = out + 1 + (long)iB * NP1;
    orowA[j0]     = eA0 * invA;
    orowA[j0 + 1] = eA1 * invA;
    orowB[j0]     = eB0 * invB;
    orowB[j0 + 1] = eB1 * invB;
    if (tid == 0) {
        orowA[1024] = e4A * invA;
        orowB[1024] = e4B * invB;
    }
    #undef LDX
}

extern "C" void kernel_launch(void* const* d_in, const int* in_sizes, int n_in,
                              void* d_out, int out_size, void* d_ws, size_t ws_size,
                              hipStream_t stream) {
    const float* sentence = (const float*)d_in[0];
    const int*   target   = (const int*)  d_in[1];
    const float* W1       = (const float*)d_in[2];
    const float* b1       = (const float*)d_in[3];
    const float* W2       = (const float*)d_in[4];
    const float* b2       = (const float*)d_in[5];
    float* out = (float*)d_out;

    float* s1b = (float*)d_ws;                 // 1024*100
    float* s2T = s1b + NN * MID;               // 100*1088
    float* W1T = s2T + MID * SST;              // 600*100

    transpose_kernel<<<(2 * H + 63) / 64, 256, 0, stream>>>(W1, W1T, out);
    precompute_kernel<<<NN / 2, 256, 0, stream>>>(sentence, W1T, b1, s1b, s2T);
    main_kernel<<<NN / 2, 512, 0, stream>>>(s1b, s2T, W2, b2, target, out);
}

// Round 6
// 112.270 us; speedup vs baseline: 1.9935x; 1.1110x over previous
//
#include <hip/hip_runtime.h>

#define H     300
#define MID   100
#define NN    1024
#define NP1   1025
#define SST   1088   // padded s2T row stride (4352 B, 256B-aligned rows)

// paired contribution: acc += w_a*sig(x_a,apre_a) + w_b*sig(x_b,apre_b), ONE rcp:
// w_a/A + w_b/B = (w_a*B + w_b*A) * rcp(A*B),  A=1+exp2(fma(x_a,NL,apre_a)), etc.
static __device__ __forceinline__ void pair_acc(
    float x_a, float x_b, float apre_a, float apre_b,
    float w_a, float w_b, float& acc)
{
    const float NL = -1.4426950408889634f;
    const float A = 1.0f + __builtin_amdgcn_exp2f(__builtin_fmaf(x_a, NL, apre_a));
    const float B = 1.0f + __builtin_amdgcn_exp2f(__builtin_fmaf(x_b, NL, apre_b));
    acc = __builtin_fmaf(__builtin_fmaf(w_a, B, w_b * A),
                         __builtin_amdgcn_rcpf(A * B), acc);
}

static __device__ __forceinline__ float sig_pre(float x, float apre) {
    const float NL = -1.4426950408889634f;
    return __builtin_amdgcn_rcpf(1.0f + __builtin_amdgcn_exp2f(__builtin_fmaf(x, NL, apre)));
}

// ---------------------------------------------------------------------------
// Kernel A (merged): precompute s1b / s2T straight from row-major W1 —
// no transpose kernel, no W1T round-trip.
// 512 blocks x 256 threads; block b -> items iA=2b, iB=2b+1.
// Each wave is split into two 32-lane groups; each group owns one m at a
// time and strides lanes over h, so W1 reads are 128B-contiguous per group
// (coalesced). Sentence rows live in LDS (broadcast reads). A 5-step
// __shfl_xor butterfly reduces each dot. Waves 0,1 -> W1 first half -> s1b;
// waves 2,3 -> second half -> s2T. Also zeroes out[0] and s2T column 0.
// ---------------------------------------------------------------------------
__global__ __launch_bounds__(256) void precompute_kernel(
    const float* __restrict__ sentence,
    const float* __restrict__ W1,
    const float* __restrict__ b1,
    float* __restrict__ s1b,
    float* __restrict__ s2T,
    float* __restrict__ out)
{
    __shared__ float rA[H];
    __shared__ float rB[H];
    const int tid = threadIdx.x;
    const int iA = blockIdx.x * 2, iB = iA + 1;

    if (blockIdx.x == 0) {
        if (tid == 0) out[0] = 0.0f;                 // loss accumulator
        if (tid < MID) s2T[(long)tid * SST] = 0.0f;  // pm[0] = zeros column
    }

    const float* sA = sentence + (long)iA * H;
    const float* sB = sentence + (long)iB * H;
    for (int idx = tid; idx < 2 * H; idx += 256) {
        if (idx < H) rA[idx] = sA[idx];
        else         rB[idx - H] = sB[idx - H];
    }
    __syncthreads();

    const int wv   = tid >> 6;       // wave 0..3
    const int lane = tid & 63;
    const int sub  = lane >> 5;      // which m of the pair (0/1)
    const int hb   = lane & 31;      // h-lane within the 32-group
    const int half = wv >> 1;        // 0: W1[:, :300] -> s1 ; 1: W1[:, 300:] -> s2
    const int mb   = (wv & 1) * 50;  // m range base for this wave

    for (int q = 0; q < 25; ++q) {
        const int m = mb + 2 * q + sub;
        const float* wrow = W1 + (long)m * (2 * H) + half * H;
        float aA = 0.f, aB = 0.f;
        #pragma unroll
        for (int k = 0; k < 9; ++k) {
            const int h = hb + 32 * k;
            const float w = wrow[h];
            aA = __builtin_fmaf(w, rA[h], aA);
            aB = __builtin_fmaf(w, rB[h], aB);
        }
        if (hb < 12) {               // tail: h = 288..299
            const int h = hb + 288;
            const float w = wrow[h];
            aA = __builtin_fmaf(w, rA[h], aA);
            aB = __builtin_fmaf(w, rB[h], aB);
        }
        #pragma unroll
        for (int off = 16; off > 0; off >>= 1) {
            aA += __shfl_xor(aA, off, 64);
            aB += __shfl_xor(aB, off, 64);
        }
        if (hb == 0) {
            if (half == 0) {
                const float bb = b1[m];
                s1b[iA * MID + m] = aA + bb;
                s1b[iB * MID + m] = aB + bb;
            } else {
                s2T[(long)m * SST + (iA + 1)] = aA;   // odd index: scalar stores
                s2T[(long)m * SST + (iB + 1)] = aB;
            }
        }
    }
}

// ---------------------------------------------------------------------------
// Kernel B: 512 blocks x 512 threads (16 waves/CU = 4 waves/SIMD).
// Block handles rows iA=2b, iB=2b+1; thread handles 2 consecutive cols
// (j = 2*tid, 2*tid+1) via float2 loads (4 sigmoids/load, 210 MB L2 traffic).
// m-loop processed in pairs with the shared-rcp trick; distance-2 pipeline.
// ---------------------------------------------------------------------------
__global__ __launch_bounds__(512, 4) void main_kernel(
    const float* __restrict__ s1b,
    const float* __restrict__ s2T,
    const float* __restrict__ W2,
    const float* __restrict__ b2,
    const int*   __restrict__ target,
    float* __restrict__ out)
{
    __shared__ float4 aw4[MID];        // {apreA[m], apreB[m], W2[m], 0}
    __shared__ float tmpA[MID], tmpB[MID];
    __shared__ float r1[8], r2[8], r3[8];
    __shared__ float bc[4];
    __shared__ float sc4sh[2];

    const int iA = blockIdx.x * 2, iB = iA + 1;
    const int tid = threadIdx.x;
    const int lane = tid & 63, wv = tid >> 6;
    const float NL  = -1.4426950408889634f;
    const float L2E =  1.4426950408889634f;

    if (tid < MID)
        aw4[tid] = make_float4(s1b[iA * MID + tid] * NL,
                               s1b[iB * MID + tid] * NL,
                               W2[tid], 0.f);
    const float b2v = b2[0];
    __syncthreads();

    const long colbase = (long)(tid << 1);
    #define LDX(m) (*(const float2*)(s2T + (long)(m) * SST + colbase))

    float aA0 = 0.f, aA1 = 0.f, aB0 = 0.f, aB1 = 0.f;

    // pairs p: m = 2p, 2p+1. Prefetch 2 pairs ahead.
    float2 x0 = LDX(0), x1 = LDX(1);
    float2 x2 = LDX(2), x3 = LDX(3);
    #pragma unroll 2
    for (int p = 0; p < 48; ++p) {
        const float2 xn0 = LDX(2 * p + 4);
        const float2 xn1 = LDX(2 * p + 5);
        const float4 wA = aw4[2 * p];
        const float4 wB = aw4[2 * p + 1];
        pair_acc(x0.x, x1.x, wA.x, wB.x, wA.z, wB.z, aA0);
        pair_acc(x0.y, x1.y, wA.x, wB.x, wA.z, wB.z, aA1);
        pair_acc(x0.x, x1.x, wA.y, wB.y, wA.z, wB.z, aB0);
        pair_acc(x0.y, x1.y, wA.y, wB.y, wA.z, wB.z, aB1);
        x0 = x2; x1 = x3; x2 = xn0; x3 = xn1;
    }
    {
        float4 wA = aw4[96], wB = aw4[97];
        pair_acc(x0.x, x1.x, wA.x, wB.x, wA.z, wB.z, aA0);
        pair_acc(x0.y, x1.y, wA.x, wB.x, wA.z, wB.z, aA1);
        pair_acc(x0.x, x1.x, wA.y, wB.y, wA.z, wB.z, aB0);
        pair_acc(x0.y, x1.y, wA.y, wB.y, wA.z, wB.z, aB1);
        wA = aw4[98]; wB = aw4[99];
        pair_acc(x2.x, x3.x, wA.x, wB.x, wA.z, wB.z, aA0);
        pair_acc(x2.y, x3.y, wA.x, wB.x, wA.z, wB.z, aA1);
        pair_acc(x2.x, x3.x, wA.y, wB.y, wA.z, wB.z, aB0);
        pair_acc(x2.y, x3.y, wA.y, wB.y, wA.z, wB.z, aB1);
    }

    const float scA0 = aA0 + b2v, scA1 = aA1 + b2v;
    const float scB0 = aB0 + b2v, scB1 = aB1 + b2v;

    // ---- remainder column j = 1024 ----
    if (tid < MID) {
        const float4 w = aw4[tid];
        const float x = s2T[(long)tid * SST + 1024];
        tmpA[tid] = w.z * sig_pre(x, w.x);
        tmpB[tid] = w.z * sig_pre(x, w.y);
    }
    __syncthreads();
    if (wv == 0) {
        float v = tmpA[lane] + ((lane < MID - 64) ? tmpA[lane + 64] : 0.f);
        #pragma unroll
        for (int off = 32; off > 0; off >>= 1) v += __shfl_down(v, off);
        if (lane == 0) sc4sh[0] = v + b2v;
    } else if (wv == 1) {
        float v = tmpB[lane] + ((lane < MID - 64) ? tmpB[lane + 64] : 0.f);
        #pragma unroll
        for (int off = 32; off > 0; off >>= 1) v += __shfl_down(v, off);
        if (lane == 0) sc4sh[1] = v + b2v;
    }
    __syncthreads();
    const float sc4A = sc4sh[0];
    const float sc4B = sc4sh[1];

    // ---- loss + row-max ----
    const int tgtA = target[iA], tgtB = target[iB];
    const int j0 = tid << 1;
    float ls = fabsf(scA0 - ((j0     == tgtA) ? 1.f : 0.f))
             + fabsf(scA1 - ((j0 + 1 == tgtA) ? 1.f : 0.f))
             + fabsf(scB0 - ((j0     == tgtB) ? 1.f : 0.f))
             + fabsf(scB1 - ((j0 + 1 == tgtB) ? 1.f : 0.f));
    float mA = fmaxf(scA0, scA1);
    float mB = fmaxf(scB0, scB1);
    if (tid == 0) {
        ls += fabsf(sc4A - ((1024 == tgtA) ? 1.f : 0.f))
            + fabsf(sc4B - ((1024 == tgtB) ? 1.f : 0.f));
        mA = fmaxf(mA, sc4A);
        mB = fmaxf(mB, sc4B);
    }
    #pragma unroll
    for (int off = 32; off > 0; off >>= 1) {
        ls += __shfl_down(ls, off);
        mA = fmaxf(mA, __shfl_down(mA, off));
        mB = fmaxf(mB, __shfl_down(mB, off));
    }
    if (lane == 0) { r1[wv] = ls; r2[wv] = mA; r3[wv] = mB; }
    __syncthreads();
    if (tid == 0) {
        float L = 0.f, MA = -1e30f, MB = -1e30f;
        #pragma unroll
        for (int k = 0; k < 8; ++k) {
            L += r1[k];
            MA = fmaxf(MA, r2[k]);
            MB = fmaxf(MB, r3[k]);
        }
        atomicAdd(out, L * (1.0f / ((float)NN * (float)NP1)));
        bc[0] = MA;
        bc[1] = MB;
    }
    __syncthreads();
    const float rmA = bc[0], rmB = bc[1];

    // ---- exp + sum per row ----
    const float eA0 = __builtin_amdgcn_exp2f((scA0 - rmA) * L2E);
    const float eA1 = __builtin_amdgcn_exp2f((scA1 - rmA) * L2E);
    const float eB0 = __builtin_amdgcn_exp2f((scB0 - rmB) * L2E);
    const float eB1 = __builtin_amdgcn_exp2f((scB1 - rmB) * L2E);
    float e4A = 0.f, e4B = 0.f;
    if (tid == 0) {
        e4A = __builtin_amdgcn_exp2f((sc4A - rmA) * L2E);
        e4B = __builtin_amdgcn_exp2f((sc4B - rmB) * L2E);
    }
    float esA = eA0 + eA1 + e4A;
    float esB = eB0 + eB1 + e4B;
    #pragma unroll
    for (int off = 32; off > 0; off >>= 1) {
        esA += __shfl_down(esA, off);
        esB += __shfl_down(esB, off);
    }
    if (lane == 0) { r1[wv] = esA; r2[wv] = esB; }
    __syncthreads();
    if (tid == 0) {
        float SA = 0.f, SB = 0.f;
        #pragma unroll
        for (int k = 0; k < 8; ++k) { SA += r1[k]; SB += r2[k]; }
        bc[2] = 1.0f / SA;
        bc[3] = 1.0f / SB;
    }
    __syncthreads();
    const float invA = bc[2], invB = bc[3];

    // ---- write softmax rows ----
    float* orowA = out + 1 + (long)iA * NP1;
    float* orowB = out + 1 + (long)iB * NP1;
    orowA[j0]     = eA0 * invA;
    orowA[j0 + 1] = eA1 * invA;
    orowB[j0]     = eB0 * invB;
    orowB[j0 + 1] = eB1 * invB;
    if (tid == 0) {
        orowA[1024] = e4A * invA;
        orowB[1024] = e4B * invB;
    }
    #undef LDX
}

extern "C" void kernel_launch(void* const* d_in, const int* in_sizes, int n_in,
                              void* d_out, int out_size, void* d_ws, size_t ws_size,
                              hipStream_t stream) {
    const float* sentence = (const float*)d_in[0];
    const int*   target   = (const int*)  d_in[1];
    const float* W1       = (const float*)d_in[2];
    const float* b1       = (const float*)d_in[3];
    const float* W2       = (const float*)d_in[4];
    const float* b2       = (const float*)d_in[5];
    float* out = (float*)d_out;

    float* s1b = (float*)d_ws;                 // 1024*100
    float* s2T = s1b + NN * MID;               // 100*1088 (padded stride)

    precompute_kernel<<<NN / 2, 256, 0, stream>>>(sentence, W1, b1, s1b, s2T, out);
    main_kernel<<<NN / 2, 512, 0, stream>>>(s1b, s2T, W2, b2, target, out);
}

// Round 7
// 106.596 us; speedup vs baseline: 2.0996x; 1.0532x over previous
//
#include <hip/hip_runtime.h>

#define H     300
#define MID   100
#define NN    1024
#define NP1   1025
#define SST   1088   // padded s2T row stride (4352 B, 256B-aligned rows)

// ---------------------------------------------------------------------------
// Kernel A: precompute s1b / s2T straight from row-major W1 (no transpose).
// 512 blocks x 256 threads; block b -> items iA=2b, iB=2b+1.
// Each wave splits into two 32-lane groups; each group owns one m and strides
// lanes over h (128B-contiguous coalesced W1 reads). Sentence rows in LDS.
// 5-step __shfl_xor butterfly per dot. Waves 0,1 -> s1b; waves 2,3 -> s2T.
// ---------------------------------------------------------------------------
__global__ __launch_bounds__(256) void precompute_kernel(
    const float* __restrict__ sentence,
    const float* __restrict__ W1,
    const float* __restrict__ b1,
    float* __restrict__ s1b,
    float* __restrict__ s2T,
    float* __restrict__ out)
{
    __shared__ float rA[H];
    __shared__ float rB[H];
    const int tid = threadIdx.x;
    const int iA = blockIdx.x * 2, iB = iA + 1;

    if (blockIdx.x == 0) {
        if (tid == 0) out[0] = 0.0f;                 // loss accumulator
        if (tid < MID) s2T[(long)tid * SST] = 0.0f;  // pm[0] = zeros column
    }

    const float* sA = sentence + (long)iA * H;
    const float* sB = sentence + (long)iB * H;
    for (int idx = tid; idx < 2 * H; idx += 256) {
        if (idx < H) rA[idx] = sA[idx];
        else         rB[idx - H] = sB[idx - H];
    }
    __syncthreads();

    const int wv   = tid >> 6;
    const int lane = tid & 63;
    const int sub  = lane >> 5;
    const int hb   = lane & 31;
    const int half = wv >> 1;
    const int mb   = (wv & 1) * 50;

    for (int q = 0; q < 25; ++q) {
        const int m = mb + 2 * q + sub;
        const float* wrow = W1 + (long)m * (2 * H) + half * H;
        float aA = 0.f, aB = 0.f;
        #pragma unroll
        for (int k = 0; k < 9; ++k) {
            const int h = hb + 32 * k;
            const float w = wrow[h];
            aA = __builtin_fmaf(w, rA[h], aA);
            aB = __builtin_fmaf(w, rB[h], aB);
        }
        if (hb < 12) {
            const int h = hb + 288;
            const float w = wrow[h];
            aA = __builtin_fmaf(w, rA[h], aA);
            aB = __builtin_fmaf(w, rB[h], aB);
        }
        #pragma unroll
        for (int off = 16; off > 0; off >>= 1) {
            aA += __shfl_xor(aA, off, 64);
            aB += __shfl_xor(aB, off, 64);
        }
        if (hb == 0) {
            if (half == 0) {
                const float bb = b1[m];
                s1b[iA * MID + m] = aA + bb;
                s1b[iB * MID + m] = aB + bb;
            } else {
                s2T[(long)m * SST + (iA + 1)] = aA;
                s2T[(long)m * SST + (iB + 1)] = aB;
            }
        }
    }
}

// ---------------------------------------------------------------------------
// Kernel B: 256 blocks x 1024 threads (16 waves/CU = 4 waves/SIMD).
// Block handles 4 rows i0..i0+3; thread handles ONE column j = tid.
// sigmoid(s1+x) = 1/(1 + E*F), E = exp2(x*NL) shared across the 4 rows,
// F = exp2(s1*NL) precomputed once per row into LDS (Fq[m] = 4 rows).
// m processed in pairs with the shared-rcp trick:
//   w0/A + w1/B = fma(w0, B, w1*A) * rcp(A*B),  A=fma(E0,F0,1), B=fma(E1,F1,1)
// Cost/sigmoid ~= 0.25 exp2 + 0.5 rcp + 3 VALU  (~11.8 issue-cyc).
// ---------------------------------------------------------------------------
__global__ __launch_bounds__(1024, 4) void main_kernel(
    const float* __restrict__ s1b,
    const float* __restrict__ s2T,
    const float* __restrict__ W2,
    const float* __restrict__ b2,
    const int*   __restrict__ target,
    float* __restrict__ out)
{
    __shared__ float4 Fq[MID];          // {F0,F1,F2,F3}[m]
    __shared__ float2 w2sh[MID / 2];    // {W2[2p], W2[2p+1]}
    __shared__ float  tmp[4][104];      // remainder-column partials per row
    __shared__ float  redl[16];
    __shared__ float4 redm[16];
    __shared__ float4 rede[16];
    __shared__ float  sc4sh[4];
    __shared__ float4 bmax, binv;

    const int i0  = blockIdx.x * 4;
    const int tid = threadIdx.x;
    const int lane = tid & 63, wv = tid >> 6;
    const float NL  = -1.4426950408889634f;
    const float L2E =  1.4426950408889634f;

    if (tid < MID) {
        Fq[tid] = make_float4(
            __builtin_amdgcn_exp2f(s1b[(i0 + 0) * MID + tid] * NL),
            __builtin_amdgcn_exp2f(s1b[(i0 + 1) * MID + tid] * NL),
            __builtin_amdgcn_exp2f(s1b[(i0 + 2) * MID + tid] * NL),
            __builtin_amdgcn_exp2f(s1b[(i0 + 3) * MID + tid] * NL));
    } else if (tid >= 128 && tid < 128 + MID / 2) {
        const int p = tid - 128;
        w2sh[p] = make_float2(W2[2 * p], W2[2 * p + 1]);
    }
    const float b2v = b2[0];
    __syncthreads();

    const float* col = s2T + tid;
    #define LDX(m) col[(long)(m) * SST]

    float a0 = 0.f, a1 = 0.f, a2 = 0.f, a3 = 0.f;

    #define PBODY(p_, X0, X1)                                              \
        do {                                                               \
            const float E0 = __builtin_amdgcn_exp2f((X0) * NL);            \
            const float E1 = __builtin_amdgcn_exp2f((X1) * NL);            \
            const float4 F0 = Fq[2 * (p_)];                                \
            const float4 F1 = Fq[2 * (p_) + 1];                            \
            const float2 w  = w2sh[p_];                                    \
            {                                                              \
                const float A = __builtin_fmaf(E0, F0.x, 1.f);             \
                const float B = __builtin_fmaf(E1, F1.x, 1.f);             \
                a0 = __builtin_fmaf(__builtin_fmaf(w.x, B, w.y * A),       \
                                    __builtin_amdgcn_rcpf(A * B), a0);     \
            }                                                              \
            {                                                              \
                const float A = __builtin_fmaf(E0, F0.y, 1.f);             \
                const float B = __builtin_fmaf(E1, F1.y, 1.f);             \
                a1 = __builtin_fmaf(__builtin_fmaf(w.x, B, w.y * A),       \
                                    __builtin_amdgcn_rcpf(A * B), a1);     \
            }                                                              \
            {                                                              \
                const float A = __builtin_fmaf(E0, F0.z, 1.f);             \
                const float B = __builtin_fmaf(E1, F1.z, 1.f);             \
                a2 = __builtin_fmaf(__builtin_fmaf(w.x, B, w.y * A),       \
                                    __builtin_amdgcn_rcpf(A * B), a2);     \
            }                                                              \
            {                                                              \
                const float A = __builtin_fmaf(E0, F0.w, 1.f);             \
                const float B = __builtin_fmaf(E1, F1.w, 1.f);             \
                a3 = __builtin_fmaf(__builtin_fmaf(w.x, B, w.y * A),       \
                                    __builtin_amdgcn_rcpf(A * B), a3);     \
            }                                                              \
        } while (0)

    // 50 m-pairs, distance-2 pipeline on the scalar column loads
    float x0 = LDX(0), x1 = LDX(1), x2 = LDX(2), x3 = LDX(3);
    #pragma unroll 2
    for (int p = 0; p < 48; ++p) {
        const float xn0 = LDX(2 * p + 4);
        const float xn1 = LDX(2 * p + 5);
        PBODY(p, x0, x1);
        x0 = x2; x1 = x3; x2 = xn0; x3 = xn1;
    }
    PBODY(48, x0, x1);
    PBODY(49, x2, x3);

    const float sc0 = a0 + b2v, sc1 = a1 + b2v, sc2 = a2 + b2v, sc3 = a3 + b2v;

    // ---- remainder column j = 1024 (4 rows) ----
    if (tid < MID) {
        const float x = s2T[(long)tid * SST + 1024];
        const float E = __builtin_amdgcn_exp2f(x * NL);
        const float4 F = Fq[tid];
        const float wm = W2[tid];
        tmp[0][tid] = wm * __builtin_amdgcn_rcpf(__builtin_fmaf(E, F.x, 1.f));
        tmp[1][tid] = wm * __builtin_amdgcn_rcpf(__builtin_fmaf(E, F.y, 1.f));
        tmp[2][tid] = wm * __builtin_amdgcn_rcpf(__builtin_fmaf(E, F.z, 1.f));
        tmp[3][tid] = wm * __builtin_amdgcn_rcpf(__builtin_fmaf(E, F.w, 1.f));
    }
    __syncthreads();
    if (wv < 4) {
        float v = tmp[wv][lane] + ((lane < MID - 64) ? tmp[wv][lane + 64] : 0.f);
        #pragma unroll
        for (int off = 32; off > 0; off >>= 1) v += __shfl_down(v, off);
        if (lane == 0) sc4sh[wv] = v + b2v;
    }
    __syncthreads();

    // ---- loss + row-max ----
    const int tg0 = target[i0], tg1 = target[i0 + 1];
    const int tg2 = target[i0 + 2], tg3 = target[i0 + 3];
    float ls = fabsf(sc0 - ((tid == tg0) ? 1.f : 0.f))
             + fabsf(sc1 - ((tid == tg1) ? 1.f : 0.f))
             + fabsf(sc2 - ((tid == tg2) ? 1.f : 0.f))
             + fabsf(sc3 - ((tid == tg3) ? 1.f : 0.f));
    float4 mx = make_float4(sc0, sc1, sc2, sc3);
    if (tid == 0) {
        ls += fabsf(sc4sh[0] - ((1024 == tg0) ? 1.f : 0.f))
            + fabsf(sc4sh[1] - ((1024 == tg1) ? 1.f : 0.f))
            + fabsf(sc4sh[2] - ((1024 == tg2) ? 1.f : 0.f))
            + fabsf(sc4sh[3] - ((1024 == tg3) ? 1.f : 0.f));
        mx.x = fmaxf(mx.x, sc4sh[0]);
        mx.y = fmaxf(mx.y, sc4sh[1]);
        mx.z = fmaxf(mx.z, sc4sh[2]);
        mx.w = fmaxf(mx.w, sc4sh[3]);
    }
    #pragma unroll
    for (int off = 32; off > 0; off >>= 1) {
        ls += __shfl_down(ls, off);
        mx.x = fmaxf(mx.x, __shfl_down(mx.x, off));
        mx.y = fmaxf(mx.y, __shfl_down(mx.y, off));
        mx.z = fmaxf(mx.z, __shfl_down(mx.z, off));
        mx.w = fmaxf(mx.w, __shfl_down(mx.w, off));
    }
    if (lane == 0) { redl[wv] = ls; redm[wv] = mx; }
    __syncthreads();
    if (tid == 0) {
        float L = 0.f;
        float4 M = make_float4(-1e30f, -1e30f, -1e30f, -1e30f);
        #pragma unroll
        for (int k = 0; k < 16; ++k) {
            L += redl[k];
            M.x = fmaxf(M.x, redm[k].x);
            M.y = fmaxf(M.y, redm[k].y);
            M.z = fmaxf(M.z, redm[k].z);
            M.w = fmaxf(M.w, redm[k].w);
        }
        atomicAdd(out, L * (1.0f / ((float)NN * (float)NP1)));
        bmax = M;
    }
    __syncthreads();
    const float4 rm = bmax;

    // ---- exp + sum per row ----
    const float e0 = __builtin_amdgcn_exp2f((sc0 - rm.x) * L2E);
    const float e1 = __builtin_amdgcn_exp2f((sc1 - rm.y) * L2E);
    const float e2 = __builtin_amdgcn_exp2f((sc2 - rm.z) * L2E);
    const float e3 = __builtin_amdgcn_exp2f((sc3 - rm.w) * L2E);
    float4 e4v = make_float4(0.f, 0.f, 0.f, 0.f);
    if (tid == 0) {
        e4v.x = __builtin_amdgcn_exp2f((sc4sh[0] - rm.x) * L2E);
        e4v.y = __builtin_amdgcn_exp2f((sc4sh[1] - rm.y) * L2E);
        e4v.z = __builtin_amdgcn_exp2f((sc4sh[2] - rm.z) * L2E);
        e4v.w = __builtin_amdgcn_exp2f((sc4sh[3] - rm.w) * L2E);
    }
    float4 es = make_float4(e0 + e4v.x, e1 + e4v.y, e2 + e4v.z, e3 + e4v.w);
    #pragma unroll
    for (int off = 32; off > 0; off >>= 1) {
        es.x += __shfl_down(es.x, off);
        es.y += __shfl_down(es.y, off);
        es.z += __shfl_down(es.z, off);
        es.w += __shfl_down(es.w, off);
    }
    if (lane == 0) rede[wv] = es;
    __syncthreads();
    if (tid == 0) {
        float4 S = make_float4(0.f, 0.f, 0.f, 0.f);
        #pragma unroll
        for (int k = 0; k < 16; ++k) {
            S.x += rede[k].x; S.y += rede[k].y;
            S.z += rede[k].z; S.w += rede[k].w;
        }
        binv = make_float4(1.f / S.x, 1.f / S.y, 1.f / S.z, 1.f / S.w);
    }
    __syncthreads();
    const float4 iv = binv;

    // ---- write softmax rows ----
    float* o0 = out + 1 + (long)(i0 + 0) * NP1;
    float* o1 = out + 1 + (long)(i0 + 1) * NP1;
    float* o2 = out + 1 + (long)(i0 + 2) * NP1;
    float* o3 = out + 1 + (long)(i0 + 3) * NP1;
    o0[tid] = e0 * iv.x;
    o1[tid] = e1 * iv.y;
    o2[tid] = e2 * iv.z;
    o3[tid] = e3 * iv.w;
    if (tid == 0) {
        o0[1024] = e4v.x * iv.x;
        o1[1024] = e4v.y * iv.y;
        o2[1024] = e4v.z * iv.z;
        o3[1024] = e4v.w * iv.w;
    }
    #undef PBODY
    #undef LDX
}

extern "C" void kernel_launch(void* const* d_in, const int* in_sizes, int n_in,
                              void* d_out, int out_size, void* d_ws, size_t ws_size,
                              hipStream_t stream) {
    const float* sentence = (const float*)d_in[0];
    const int*   target   = (const int*)  d_in[1];
    const float* W1       = (const float*)d_in[2];
    const float* b1       = (const float*)d_in[3];
    const float* W2       = (const float*)d_in[4];
    const float* b2       = (const float*)d_in[5];
    float* out = (float*)d_out;

    float* s1b = (float*)d_ws;                 // 1024*100
    float* s2T = s1b + NN * MID;               // 100*1088 (padded stride)

    precompute_kernel<<<NN / 2, 256, 0, stream>>>(sentence, W1, b1, s1b, s2T, out);
    main_kernel<<<NN / 4, 1024, 0, stream>>>(s1b, s2T, W2, b2, target, out);
}

// Round 8
// 102.685 us; speedup vs baseline: 2.1795x; 1.0381x over previous
//
#include <hip/hip_runtime.h>

#define H     300
#define MID   100
#define NN    1024
#define NP1   1025
#define JST   1088   // padded j-extent of E4 (E4[25][1088][4] floats)

// ---------------------------------------------------------------------------
// Kernel A: precompute s1b and E4 straight from row-major W1.
// 512 blocks x 256 threads; block b -> items iA=2b, iB=2b+1.
// Each wave splits into two 32-lane groups; each group owns one m and strides
// lanes over h (128B-contiguous coalesced W1 reads). Sentence rows in LDS.
// 5-step __shfl_xor butterfly per dot. Waves 0,1 -> s1b rows (s1 = dot+b1).
// Waves 2,3 -> E4[m>>2][j][m&3] = exp2(s2 * -log2e)   (j = item+1).
// E for column j=0 (pm[0]=zeros) is exp2(0)=1.0, seeded by block 0.
// ---------------------------------------------------------------------------
__global__ __launch_bounds__(256) void precompute_kernel(
    const float* __restrict__ sentence,
    const float* __restrict__ W1,
    const float* __restrict__ b1,
    float* __restrict__ s1b,
    float* __restrict__ E4,
    float* __restrict__ out)
{
    __shared__ float rA[H];
    __shared__ float rB[H];
    const int tid = threadIdx.x;
    const int iA = blockIdx.x * 2, iB = iA + 1;
    const float NL = -1.4426950408889634f;

    if (blockIdx.x == 0) {
        if (tid == 0) out[0] = 0.0f;                              // loss accumulator
        if (tid < MID)
            E4[(long)((tid >> 2) * JST) * 4 + (tid & 3)] = 1.0f;  // j=0 column
    }

    const float* sA = sentence + (long)iA * H;
    const float* sB = sentence + (long)iB * H;
    for (int idx = tid; idx < 2 * H; idx += 256) {
        if (idx < H) rA[idx] = sA[idx];
        else         rB[idx - H] = sB[idx - H];
    }
    __syncthreads();

    const int wv   = tid >> 6;
    const int lane = tid & 63;
    const int sub  = lane >> 5;
    const int hb   = lane & 31;
    const int half = wv >> 1;
    const int mb   = (wv & 1) * 50;

    for (int q = 0; q < 25; ++q) {
        const int m = mb + 2 * q + sub;
        const float* wrow = W1 + (long)m * (2 * H) + half * H;
        float aA = 0.f, aB = 0.f;
        #pragma unroll
        for (int k = 0; k < 9; ++k) {
            const int h = hb + 32 * k;
            const float w = wrow[h];
            aA = __builtin_fmaf(w, rA[h], aA);
            aB = __builtin_fmaf(w, rB[h], aB);
        }
        if (hb < 12) {
            const int h = hb + 288;
            const float w = wrow[h];
            aA = __builtin_fmaf(w, rA[h], aA);
            aB = __builtin_fmaf(w, rB[h], aB);
        }
        #pragma unroll
        for (int off = 16; off > 0; off >>= 1) {
            aA += __shfl_xor(aA, off, 64);
            aB += __shfl_xor(aB, off, 64);
        }
        if (hb == 0) {
            if (half == 0) {
                const float bb = b1[m];
                s1b[iA * MID + m] = aA + bb;
                s1b[iB * MID + m] = aB + bb;
            } else {
                float* base = E4 + (long)((m >> 2) * JST) * 4 + (m & 3);
                base[(long)(iA + 1) * 4] = __builtin_amdgcn_exp2f(aA * NL);
                base[(long)(iB + 1) * 4] = __builtin_amdgcn_exp2f(aB * NL);
            }
        }
    }
}

// ---------------------------------------------------------------------------
// Kernel B: 256 blocks x 1024 threads (16 waves/CU = 4 waves/SIMD).
// Block handles 4 rows i0..i0+3; thread handles ONE column j = tid.
// sigmoid(s1+x) = 1/(1 + E*F): E pre-stored (E4, float4 per m-quad, coalesced),
// F = exp2(s1*NL) per row in LDS. Quad-rcp: for m-quad with A=fma(E,F,1) etc:
//   w0/A+w1/B+w2/C+w3/D = [fma(w0,B,w1*A)*CD + fma(w2,D,w3*C)*AB] * rcp(ABCD)
// -> 14 VALU + 1 rcp per 4 sigmoids per row; E-exp2 cost moved to kernel A.
// ---------------------------------------------------------------------------
__global__ __launch_bounds__(1024, 4) void main_kernel(
    const float* __restrict__ s1b,
    const float* __restrict__ E4,
    const float* __restrict__ W2,
    const float* __restrict__ b2,
    const int*   __restrict__ target,
    float* __restrict__ out)
{
    __shared__ float4 Fq[MID];          // {F_row0..F_row3}[m]
    __shared__ float4 w4sh[MID / 4];    // W2 m-quads
    __shared__ float  tmp[4][104];      // remainder-column partials per row
    __shared__ float  redl[16];
    __shared__ float4 redm[16];
    __shared__ float4 rede[16];
    __shared__ float  sc4sh[4];
    __shared__ float4 bmax, binv;

    const int i0  = blockIdx.x * 4;
    const int tid = threadIdx.x;
    const int lane = tid & 63, wv = tid >> 6;
    const float NL  = -1.4426950408889634f;
    const float L2E =  1.4426950408889634f;

    if (tid < MID) {
        Fq[tid] = make_float4(
            __builtin_amdgcn_exp2f(s1b[(i0 + 0) * MID + tid] * NL),
            __builtin_amdgcn_exp2f(s1b[(i0 + 1) * MID + tid] * NL),
            __builtin_amdgcn_exp2f(s1b[(i0 + 2) * MID + tid] * NL),
            __builtin_amdgcn_exp2f(s1b[(i0 + 3) * MID + tid] * NL));
    } else if (tid >= 128 && tid < 128 + MID / 4) {
        const int p = tid - 128;
        w4sh[p] = make_float4(W2[4 * p], W2[4 * p + 1], W2[4 * p + 2], W2[4 * p + 3]);
    }
    const float b2v = b2[0];
    __syncthreads();

    // coalesced: lane j reads float4 at E4 + (p*JST + j)*4
    #define LDX(p_) (*(const float4*)(E4 + ((long)(p_) * JST + tid) * 4))

    float a0 = 0.f, a1 = 0.f, a2 = 0.f, a3 = 0.f;

    #define QBODY(p_, X)                                                     \
        do {                                                                 \
            const float4 F0 = Fq[4 * (p_)];                                  \
            const float4 F1 = Fq[4 * (p_) + 1];                              \
            const float4 F2 = Fq[4 * (p_) + 2];                              \
            const float4 F3 = Fq[4 * (p_) + 3];                              \
            const float4 w  = w4sh[p_];                                      \
            {                                                                \
                const float A = __builtin_fmaf((X).x, F0.x, 1.f);            \
                const float B = __builtin_fmaf((X).y, F1.x, 1.f);            \
                const float C = __builtin_fmaf((X).z, F2.x, 1.f);            \
                const float D = __builtin_fmaf((X).w, F3.x, 1.f);            \
                const float AB = A * B, CD = C * D;                          \
                const float R = __builtin_amdgcn_rcpf(AB * CD);              \
                const float n1 = __builtin_fmaf(w.x, B, w.y * A);            \
                const float n2 = __builtin_fmaf(w.z, D, w.w * C);            \
                a0 = __builtin_fmaf(__builtin_fmaf(n1, CD, n2 * AB), R, a0); \
            }                                                                \
            {                                                                \
                const float A = __builtin_fmaf((X).x, F0.y, 1.f);            \
                const float B = __builtin_fmaf((X).y, F1.y, 1.f);            \
                const float C = __builtin_fmaf((X).z, F2.y, 1.f);            \
                const float D = __builtin_fmaf((X).w, F3.y, 1.f);            \
                const float AB = A * B, CD = C * D;                          \
                const float R = __builtin_amdgcn_rcpf(AB * CD);              \
                const float n1 = __builtin_fmaf(w.x, B, w.y * A);            \
                const float n2 = __builtin_fmaf(w.z, D, w.w * C);            \
                a1 = __builtin_fmaf(__builtin_fmaf(n1, CD, n2 * AB), R, a1); \
            }                                                                \
            {                                                                \
                const float A = __builtin_fmaf((X).x, F0.z, 1.f);            \
                const float B = __builtin_fmaf((X).y, F1.z, 1.f);            \
                const float C = __builtin_fmaf((X).z, F2.z, 1.f);            \
                const float D = __builtin_fmaf((X).w, F3.z, 1.f);            \
                const float AB = A * B, CD = C * D;                          \
                const float R = __builtin_amdgcn_rcpf(AB * CD);              \
                const float n1 = __builtin_fmaf(w.x, B, w.y * A);            \
                const float n2 = __builtin_fmaf(w.z, D, w.w * C);            \
                a2 = __builtin_fmaf(__builtin_fmaf(n1, CD, n2 * AB), R, a2); \
            }                                                                \
            {                                                                \
                const float A = __builtin_fmaf((X).x, F0.w, 1.f);            \
                const float B = __builtin_fmaf((X).y, F1.w, 1.f);            \
                const float C = __builtin_fmaf((X).z, F2.w, 1.f);            \
                const float D = __builtin_fmaf((X).w, F3.w, 1.f);            \
                const float AB = A * B, CD = C * D;                          \
                const float R = __builtin_amdgcn_rcpf(AB * CD);              \
                const float n1 = __builtin_fmaf(w.x, B, w.y * A);            \
                const float n2 = __builtin_fmaf(w.z, D, w.w * C);            \
                a3 = __builtin_fmaf(__builtin_fmaf(n1, CD, n2 * AB), R, a3); \
            }                                                                \
        } while (0)

    // 25 m-quads, distance-2 software pipeline on the float4 loads
    float4 x0 = LDX(0), x1 = LDX(1);
    #pragma unroll 4
    for (int p = 0; p < 23; ++p) {
        const float4 xn = LDX(p + 2);
        QBODY(p, x0);
        x0 = x1; x1 = xn;
    }
    QBODY(23, x0);
    QBODY(24, x1);

    const float sc0 = a0 + b2v, sc1 = a1 + b2v, sc2 = a2 + b2v, sc3 = a3 + b2v;

    // ---- remainder column j = 1024 (4 rows) ----
    if (tid < MID) {
        const float E = E4[((long)(tid >> 2) * JST + 1024) * 4 + (tid & 3)];
        const float4 F = Fq[tid];
        const float wm = W2[tid];
        tmp[0][tid] = wm * __builtin_amdgcn_rcpf(__builtin_fmaf(E, F.x, 1.f));
        tmp[1][tid] = wm * __builtin_amdgcn_rcpf(__builtin_fmaf(E, F.y, 1.f));
        tmp[2][tid] = wm * __builtin_amdgcn_rcpf(__builtin_fmaf(E, F.z, 1.f));
        tmp[3][tid] = wm * __builtin_amdgcn_rcpf(__builtin_fmaf(E, F.w, 1.f));
    }
    __syncthreads();
    if (wv < 4) {
        float v = tmp[wv][lane] + ((lane < MID - 64) ? tmp[wv][lane + 64] : 0.f);
        #pragma unroll
        for (int off = 32; off > 0; off >>= 1) v += __shfl_down(v, off);
        if (lane == 0) sc4sh[wv] = v + b2v;
    }
    __syncthreads();

    // ---- loss + row-max ----
    const int tg0 = target[i0], tg1 = target[i0 + 1];
    const int tg2 = target[i0 + 2], tg3 = target[i0 + 3];
    float ls = fabsf(sc0 - ((tid == tg0) ? 1.f : 0.f))
             + fabsf(sc1 - ((tid == tg1) ? 1.f : 0.f))
             + fabsf(sc2 - ((tid == tg2) ? 1.f : 0.f))
             + fabsf(sc3 - ((tid == tg3) ? 1.f : 0.f));
    float4 mx = make_float4(sc0, sc1, sc2, sc3);
    if (tid == 0) {
        ls += fabsf(sc4sh[0] - ((1024 == tg0) ? 1.f : 0.f))
            + fabsf(sc4sh[1] - ((1024 == tg1) ? 1.f : 0.f))
            + fabsf(sc4sh[2] - ((1024 == tg2) ? 1.f : 0.f))
            + fabsf(sc4sh[3] - ((1024 == tg3) ? 1.f : 0.f));
        mx.x = fmaxf(mx.x, sc4sh[0]);
        mx.y = fmaxf(mx.y, sc4sh[1]);
        mx.z = fmaxf(mx.z, sc4sh[2]);
        mx.w = fmaxf(mx.w, sc4sh[3]);
    }
    #pragma unroll
    for (int off = 32; off > 0; off >>= 1) {
        ls += __shfl_down(ls, off);
        mx.x = fmaxf(mx.x, __shfl_down(mx.x, off));
        mx.y = fmaxf(mx.y, __shfl_down(mx.y, off));
        mx.z = fmaxf(mx.z, __shfl_down(mx.z, off));
        mx.w = fmaxf(mx.w, __shfl_down(mx.w, off));
    }
    if (lane == 0) { redl[wv] = ls; redm[wv] = mx; }
    __syncthreads();
    if (tid == 0) {
        float L = 0.f;
        float4 M = make_float4(-1e30f, -1e30f, -1e30f, -1e30f);
        #pragma unroll
        for (int k = 0; k < 16; ++k) {
            L += redl[k];
            M.x = fmaxf(M.x, redm[k].x);
            M.y = fmaxf(M.y, redm[k].y);
            M.z = fmaxf(M.z, redm[k].z);
            M.w = fmaxf(M.w, redm[k].w);
        }
        atomicAdd(out, L * (1.0f / ((float)NN * (float)NP1)));
        bmax = M;
    }
    __syncthreads();
    const float4 rm = bmax;

    // ---- exp + sum per row ----
    const float e0 = __builtin_amdgcn_exp2f((sc0 - rm.x) * L2E);
    const float e1 = __builtin_amdgcn_exp2f((sc1 - rm.y) * L2E);
    const float e2 = __builtin_amdgcn_exp2f((sc2 - rm.z) * L2E);
    const float e3 = __builtin_amdgcn_exp2f((sc3 - rm.w) * L2E);
    float4 e4v = make_float4(0.f, 0.f, 0.f, 0.f);
    if (tid == 0) {
        e4v.x = __builtin_amdgcn_exp2f((sc4sh[0] - rm.x) * L2E);
        e4v.y = __builtin_amdgcn_exp2f((sc4sh[1] - rm.y) * L2E);
        e4v.z = __builtin_amdgcn_exp2f((sc4sh[2] - rm.z) * L2E);
        e4v.w = __builtin_amdgcn_exp2f((sc4sh[3] - rm.w) * L2E);
    }
    float4 es = make_float4(e0 + e4v.x, e1 + e4v.y, e2 + e4v.z, e3 + e4v.w);
    #pragma unroll
    for (int off = 32; off > 0; off >>= 1) {
        es.x += __shfl_down(es.x, off);
        es.y += __shfl_down(es.y, off);
        es.z += __shfl_down(es.z, off);
        es.w += __shfl_down(es.w, off);
    }
    if (lane == 0) rede[wv] = es;
    __syncthreads();
    if (tid == 0) {
        float4 S = make_float4(0.f, 0.f, 0.f, 0.f);
        #pragma unroll
        for (int k = 0; k < 16; ++k) {
            S.x += rede[k].x; S.y += rede[k].y;
            S.z += rede[k].z; S.w += rede[k].w;
        }
        binv = make_float4(1.f / S.x, 1.f / S.y, 1.f / S.z, 1.f / S.w);
    }
    __syncthreads();
    const float4 iv = binv;

    // ---- write softmax rows ----
    float* o0 = out + 1 + (long)(i0 + 0) * NP1;
    float* o1 = out + 1 + (long)(i0 + 1) * NP1;
    float* o2 = out + 1 + (long)(i0 + 2) * NP1;
    float* o3 = out + 1 + (long)(i0 + 3) * NP1;
    o0[tid] = e0 * iv.x;
    o1[tid] = e1 * iv.y;
    o2[tid] = e2 * iv.z;
    o3[tid] = e3 * iv.w;
    if (tid == 0) {
        o0[1024] = e4v.x * iv.x;
        o1[1024] = e4v.y * iv.y;
        o2[1024] = e4v.z * iv.z;
        o3[1024] = e4v.w * iv.w;
    }
    #undef QBODY
    #undef LDX
}

extern "C" void kernel_launch(void* const* d_in, const int* in_sizes, int n_in,
                              void* d_out, int out_size, void* d_ws, size_t ws_size,
                              hipStream_t stream) {
    const float* sentence = (const float*)d_in[0];
    const int*   target   = (const int*)  d_in[1];
    const float* W1       = (const float*)d_in[2];
    const float* b1       = (const float*)d_in[3];
    const float* W2       = (const float*)d_in[4];
    const float* b2       = (const float*)d_in[5];
    float* out = (float*)d_out;

    float* s1b = (float*)d_ws;                 // 1024*100 floats
    float* E4  = s1b + NN * MID;               // 25*1088*4 floats

    precompute_kernel<<<NN / 2, 256, 0, stream>>>(sentence, W1, b1, s1b, E4, out);
    main_kernel<<<NN / 4, 1024, 0, stream>>>(s1b, E4, W2, b2, target, out);
}

// Round 9
// 101.619 us; speedup vs baseline: 2.2024x; 1.0105x over previous
//
#include <hip/hip_runtime.h>

#define H     300
#define MID   100
#define NN    1024
#define NP1   1025
#define JST   1088   // padded j-extent of E4 (E4[25][1088][4] floats)

typedef float v2f __attribute__((ext_vector_type(2)));
static __device__ __forceinline__ v2f sp2(float s) { return (v2f){s, s}; }
static __device__ __forceinline__ v2f fma2(v2f a, v2f b, v2f c) {
    return __builtin_elementwise_fma(a, b, c);
}

// ---------------------------------------------------------------------------
// Kernel A: precompute s1b and E4 straight from row-major W1.
// 512 blocks x 256 threads; block b -> items iA=2b, iB=2b+1.
// Each wave splits into two 32-lane groups; each group owns one m and strides
// lanes over h (128B-contiguous coalesced W1 reads). Sentence rows in LDS.
// 5-step __shfl_xor butterfly per dot. Waves 0,1 -> s1b rows (s1 = dot+b1).
// Waves 2,3 -> E4[m>>2][j][m&3] = exp2(s2 * -log2e)   (j = item+1).
// ---------------------------------------------------------------------------
__global__ __launch_bounds__(256) void precompute_kernel(
    const float* __restrict__ sentence,
    const float* __restrict__ W1,
    const float* __restrict__ b1,
    float* __restrict__ s1b,
    float* __restrict__ E4,
    float* __restrict__ out)
{
    __shared__ float rA[H];
    __shared__ float rB[H];
    const int tid = threadIdx.x;
    const int iA = blockIdx.x * 2, iB = iA + 1;
    const float NL = -1.4426950408889634f;

    if (blockIdx.x == 0) {
        if (tid == 0) out[0] = 0.0f;                              // loss accumulator
        if (tid < MID)
            E4[(long)((tid >> 2) * JST) * 4 + (tid & 3)] = 1.0f;  // j=0 column
    }

    const float* sA = sentence + (long)iA * H;
    const float* sB = sentence + (long)iB * H;
    for (int idx = tid; idx < 2 * H; idx += 256) {
        if (idx < H) rA[idx] = sA[idx];
        else         rB[idx - H] = sB[idx - H];
    }
    __syncthreads();

    const int wv   = tid >> 6;
    const int lane = tid & 63;
    const int sub  = lane >> 5;
    const int hb   = lane & 31;
    const int half = wv >> 1;
    const int mb   = (wv & 1) * 50;

    for (int q = 0; q < 25; ++q) {
        const int m = mb + 2 * q + sub;
        const float* wrow = W1 + (long)m * (2 * H) + half * H;
        float aA = 0.f, aB = 0.f;
        #pragma unroll
        for (int k = 0; k < 9; ++k) {
            const int h = hb + 32 * k;
            const float w = wrow[h];
            aA = __builtin_fmaf(w, rA[h], aA);
            aB = __builtin_fmaf(w, rB[h], aB);
        }
        if (hb < 12) {
            const int h = hb + 288;
            const float w = wrow[h];
            aA = __builtin_fmaf(w, rA[h], aA);
            aB = __builtin_fmaf(w, rB[h], aB);
        }
        #pragma unroll
        for (int off = 16; off > 0; off >>= 1) {
            aA += __shfl_xor(aA, off, 64);
            aB += __shfl_xor(aB, off, 64);
        }
        if (hb == 0) {
            if (half == 0) {
                const float bb = b1[m];
                s1b[iA * MID + m] = aA + bb;
                s1b[iB * MID + m] = aB + bb;
            } else {
                float* base = E4 + (long)((m >> 2) * JST) * 4 + (m & 3);
                base[(long)(iA + 1) * 4] = __builtin_amdgcn_exp2f(aA * NL);
                base[(long)(iB + 1) * 4] = __builtin_amdgcn_exp2f(aB * NL);
            }
        }
    }
}

// ---------------------------------------------------------------------------
// Kernel B: 256 blocks x 1024 threads (16 waves/CU = 4 waves/SIMD).
// Block handles 4 rows i0..i0+3; thread handles ONE column j = tid.
// sigmoid(s1+x) = 1/(1 + E*F): E pre-stored (E4, float4 per m-quad, coalesced),
// F = exp2(s1*NL) per row in LDS. Quad-rcp per row; rows packed in PAIRS as
// float2 ext-vectors so the symmetric VALU work lowers to v_pk_*_f32:
//   w0/A+w1/B+w2/C+w3/D = [fma(w0,B,w1*A)*CD + fma(w2,D,w3*C)*AB] * rcp(ABCD)
// ---------------------------------------------------------------------------
__global__ __launch_bounds__(1024, 4) void main_kernel(
    const float* __restrict__ s1b,
    const float* __restrict__ E4,
    const float* __restrict__ W2,
    const float* __restrict__ b2,
    const int*   __restrict__ target,
    float* __restrict__ out)
{
    __shared__ float4 Fq[MID];          // {F_row0..F_row3}[m]
    __shared__ float4 w4sh[MID / 4];    // W2 m-quads
    __shared__ float  tmp[4][104];      // remainder-column partials per row
    __shared__ float  redl[16];
    __shared__ float4 redm[16];
    __shared__ float4 rede[16];
    __shared__ float  sc4sh[4];
    __shared__ float4 bmax, binv;

    const int i0  = blockIdx.x * 4;
    const int tid = threadIdx.x;
    const int lane = tid & 63, wv = tid >> 6;
    const float NL  = -1.4426950408889634f;
    const float L2E =  1.4426950408889634f;
    const v2f one2 = sp2(1.0f);

    if (tid < MID) {
        Fq[tid] = make_float4(
            __builtin_amdgcn_exp2f(s1b[(i0 + 0) * MID + tid] * NL),
            __builtin_amdgcn_exp2f(s1b[(i0 + 1) * MID + tid] * NL),
            __builtin_amdgcn_exp2f(s1b[(i0 + 2) * MID + tid] * NL),
            __builtin_amdgcn_exp2f(s1b[(i0 + 3) * MID + tid] * NL));
    } else if (tid >= 128 && tid < 128 + MID / 4) {
        const int p = tid - 128;
        w4sh[p] = make_float4(W2[4 * p], W2[4 * p + 1], W2[4 * p + 2], W2[4 * p + 3]);
    }
    const float b2v = b2[0];
    __syncthreads();

    // coalesced: lane j reads float4 at E4 + (p*JST + j)*4
    #define LDX(p_) (*(const float4*)(E4 + ((long)(p_) * JST + tid) * 4))

    v2f acc01 = sp2(0.f), acc23 = sp2(0.f);

    #define QBODY(p_, X)                                                      \
        do {                                                                  \
            const float4 F0 = Fq[4 * (p_)];                                   \
            const float4 F1 = Fq[4 * (p_) + 1];                               \
            const float4 F2 = Fq[4 * (p_) + 2];                               \
            const float4 F3 = Fq[4 * (p_) + 3];                               \
            const float4 w  = w4sh[p_];                                       \
            const v2f e0 = sp2((X).x), e1 = sp2((X).y);                       \
            const v2f e2 = sp2((X).z), e3 = sp2((X).w);                       \
            const v2f w0 = sp2(w.x), w1 = sp2(w.y);                           \
            const v2f w2v = sp2(w.z), w3 = sp2(w.w);                          \
            {   /* rows 0,1 */                                                \
                const v2f A = fma2(e0, (v2f){F0.x, F0.y}, one2);              \
                const v2f B = fma2(e1, (v2f){F1.x, F1.y}, one2);              \
                const v2f C = fma2(e2, (v2f){F2.x, F2.y}, one2);              \
                const v2f D = fma2(e3, (v2f){F3.x, F3.y}, one2);              \
                const v2f AB = A * B, CD = C * D, P = AB * CD;                \
                const v2f R = {__builtin_amdgcn_rcpf(P.x),                    \
                               __builtin_amdgcn_rcpf(P.y)};                   \
                const v2f n1 = fma2(w0, B, w1 * A);                           \
                const v2f n2 = fma2(w2v, D, w3 * C);                          \
                acc01 = fma2(fma2(n1, CD, n2 * AB), R, acc01);                \
            }                                                                 \
            {   /* rows 2,3 */                                                \
                const v2f A = fma2(e0, (v2f){F0.z, F0.w}, one2);              \
                const v2f B = fma2(e1, (v2f){F1.z, F1.w}, one2);              \
                const v2f C = fma2(e2, (v2f){F2.z, F2.w}, one2);              \
                const v2f D = fma2(e3, (v2f){F3.z, F3.w}, one2);              \
                const v2f AB = A * B, CD = C * D, P = AB * CD;                \
                const v2f R = {__builtin_amdgcn_rcpf(P.x),                    \
                               __builtin_amdgcn_rcpf(P.y)};                   \
                const v2f n1 = fma2(w0, B, w1 * A);                           \
                const v2f n2 = fma2(w2v, D, w3 * C);                          \
                acc23 = fma2(fma2(n1, CD, n2 * AB), R, acc23);                \
            }                                                                 \
        } while (0)

    // 25 m-quads, distance-2 software pipeline on the float4 loads
    float4 x0 = LDX(0), x1 = LDX(1);
    #pragma unroll 4
    for (int p = 0; p < 23; ++p) {
        const float4 xn = LDX(p + 2);
        QBODY(p, x0);
        x0 = x1; x1 = xn;
    }
    QBODY(23, x0);
    QBODY(24, x1);

    const float sc0 = acc01.x + b2v, sc1 = acc01.y + b2v;
    const float sc2 = acc23.x + b2v, sc3 = acc23.y + b2v;

    // ---- remainder column j = 1024 (4 rows) ----
    if (tid < MID) {
        const float E = E4[((long)(tid >> 2) * JST + 1024) * 4 + (tid & 3)];
        const float4 F = Fq[tid];
        const float wm = W2[tid];
        tmp[0][tid] = wm * __builtin_amdgcn_rcpf(__builtin_fmaf(E, F.x, 1.f));
        tmp[1][tid] = wm * __builtin_amdgcn_rcpf(__builtin_fmaf(E, F.y, 1.f));
        tmp[2][tid] = wm * __builtin_amdgcn_rcpf(__builtin_fmaf(E, F.z, 1.f));
        tmp[3][tid] = wm * __builtin_amdgcn_rcpf(__builtin_fmaf(E, F.w, 1.f));
    }
    __syncthreads();
    if (wv < 4) {
        float v = tmp[wv][lane] + ((lane < MID - 64) ? tmp[wv][lane + 64] : 0.f);
        #pragma unroll
        for (int off = 32; off > 0; off >>= 1) v += __shfl_down(v, off);
        if (lane == 0) sc4sh[wv] = v + b2v;
    }
    __syncthreads();

    // ---- loss + row-max ----
    const int tg0 = target[i0], tg1 = target[i0 + 1];
    const int tg2 = target[i0 + 2], tg3 = target[i0 + 3];
    float ls = fabsf(sc0 - ((tid == tg0) ? 1.f : 0.f))
             + fabsf(sc1 - ((tid == tg1) ? 1.f : 0.f))
             + fabsf(sc2 - ((tid == tg2) ? 1.f : 0.f))
             + fabsf(sc3 - ((tid == tg3) ? 1.f : 0.f));
    float4 mx = make_float4(sc0, sc1, sc2, sc3);
    if (tid == 0) {
        ls += fabsf(sc4sh[0] - ((1024 == tg0) ? 1.f : 0.f))
            + fabsf(sc4sh[1] - ((1024 == tg1) ? 1.f : 0.f))
            + fabsf(sc4sh[2] - ((1024 == tg2) ? 1.f : 0.f))
            + fabsf(sc4sh[3] - ((1024 == tg3) ? 1.f : 0.f));
        mx.x = fmaxf(mx.x, sc4sh[0]);
        mx.y = fmaxf(mx.y, sc4sh[1]);
        mx.z = fmaxf(mx.z, sc4sh[2]);
        mx.w = fmaxf(mx.w, sc4sh[3]);
    }
    #pragma unroll
    for (int off = 32; off > 0; off >>= 1) {
        ls += __shfl_down(ls, off);
        mx.x = fmaxf(mx.x, __shfl_down(mx.x, off));
        mx.y = fmaxf(mx.y, __shfl_down(mx.y, off));
        mx.z = fmaxf(mx.z, __shfl_down(mx.z, off));
        mx.w = fmaxf(mx.w, __shfl_down(mx.w, off));
    }
    if (lane == 0) { redl[wv] = ls; redm[wv] = mx; }
    __syncthreads();
    if (tid == 0) {
        float L = 0.f;
        float4 M = make_float4(-1e30f, -1e30f, -1e30f, -1e30f);
        #pragma unroll
        for (int k = 0; k < 16; ++k) {
            L += redl[k];
            M.x = fmaxf(M.x, redm[k].x);
            M.y = fmaxf(M.y, redm[k].y);
            M.z = fmaxf(M.z, redm[k].z);
            M.w = fmaxf(M.w, redm[k].w);
        }
        atomicAdd(out, L * (1.0f / ((float)NN * (float)NP1)));
        bmax = M;
    }
    __syncthreads();
    const float4 rm = bmax;

    // ---- exp + sum per row ----
    const float e0 = __builtin_amdgcn_exp2f((sc0 - rm.x) * L2E);
    const float e1 = __builtin_amdgcn_exp2f((sc1 - rm.y) * L2E);
    const float e2 = __builtin_amdgcn_exp2f((sc2 - rm.z) * L2E);
    const float e3 = __builtin_amdgcn_exp2f((sc3 - rm.w) * L2E);
    float4 e4v = make_float4(0.f, 0.f, 0.f, 0.f);
    if (tid == 0) {
        e4v.x = __builtin_amdgcn_exp2f((sc4sh[0] - rm.x) * L2E);
        e4v.y = __builtin_amdgcn_exp2f((sc4sh[1] - rm.y) * L2E);
        e4v.z = __builtin_amdgcn_exp2f((sc4sh[2] - rm.z) * L2E);
        e4v.w = __builtin_amdgcn_exp2f((sc4sh[3] - rm.w) * L2E);
    }
    float4 es = make_float4(e0 + e4v.x, e1 + e4v.y, e2 + e4v.z, e3 + e4v.w);
    #pragma unroll
    for (int off = 32; off > 0; off >>= 1) {
        es.x += __shfl_down(es.x, off);
        es.y += __shfl_down(es.y, off);
        es.z += __shfl_down(es.z, off);
        es.w += __shfl_down(es.w, off);
    }
    if (lane == 0) rede[wv] = es;
    __syncthreads();
    if (tid == 0) {
        float4 S = make_float4(0.f, 0.f, 0.f, 0.f);
        #pragma unroll
        for (int k = 0; k < 16; ++k) {
            S.x += rede[k].x; S.y += rede[k].y;
            S.z += rede[k].z; S.w += rede[k].w;
        }
        binv = make_float4(1.f / S.x, 1.f / S.y, 1.f / S.z, 1.f / S.w);
    }
    __syncthreads();
    const float4 iv = binv;

    // ---- write softmax rows ----
    float* o0 = out + 1 + (long)(i0 + 0) * NP1;
    float* o1 = out + 1 + (long)(i0 + 1) * NP1;
    float* o2 = out + 1 + (long)(i0 + 2) * NP1;
    float* o3 = out + 1 + (long)(i0 + 3) * NP1;
    o0[tid] = e0 * iv.x;
    o1[tid] = e1 * iv.y;
    o2[tid] = e2 * iv.z;
    o3[tid] = e3 * iv.w;
    if (tid == 0) {
        o0[1024] = e4v.x * iv.x;
        o1[1024] = e4v.y * iv.y;
        o2[1024] = e4v.z * iv.z;
        o3[1024] = e4v.w * iv.w;
    }
    #undef QBODY
    #undef LDX
}

extern "C" void kernel_launch(void* const* d_in, const int* in_sizes, int n_in,
                              void* d_out, int out_size, void* d_ws, size_t ws_size,
                              hipStream_t stream) {
    const float* sentence = (const float*)d_in[0];
    const int*   target   = (const int*)  d_in[1];
    const float* W1       = (const float*)d_in[2];
    const float* b1       = (const float*)d_in[3];
    const float* W2       = (const float*)d_in[4];
    const float* b2       = (const float*)d_in[5];
    float* out = (float*)d_out;

    float* s1b = (float*)d_ws;                 // 1024*100 floats
    float* E4  = s1b + NN * MID;               // 25*1088*4 floats

    precompute_kernel<<<NN / 2, 256, 0, stream>>>(sentence, W1, b1, s1b, E4, out);
    main_kernel<<<NN / 4, 1024, 0, stream>>>(s1b, E4, W2, b2, target, out);
}